// Round 5
// baseline (186.216 us; speedup 1.0000x reference)
//
#include <hip/hip_runtime.h>

// MSDeformAttn: B=4, Lq=Lv=5440 (M=21760), C=256, heads=8, levels=4, points=4, hd=32
// Level shapes: (64,64),(32,32),(16,16),(8,8) -> starts 0,4096,5120,5376
//
// R4: launch-count / grid-size attack.
//  - R3 post-mortem: GEMM staging rewrite was NEUTRAL (138us non-sampler in both
//    R2+R3) -> GEMMs are launch/latency-bound (340-510 blocks = 1.3-2 blocks/CU,
//    6 serialized launches), not pipe-bound.
//  - prep+cvt fused into one launch; GEMM1+GEMM2 merged into one dispatch;
//    tiles 128x64 -> grids 1700/680 blocks (6.6/2.7 per CU) so resident blocks
//    overlap each other's barrier drains. 6 launches -> 4.
//  - Sampler byte-identical to R3 (47us) for attribution.

typedef __attribute__((ext_vector_type(8))) _Float16 half8;
typedef __attribute__((ext_vector_type(4))) float f32x4;

typedef __attribute__((address_space(3))) unsigned int lds_uint;
typedef const __attribute__((address_space(1))) unsigned int g_uint;

__device__ __forceinline__ void load_lds16(const _Float16* g, _Float16* l) {
    __builtin_amdgcn_global_load_lds((g_uint*)g, (lds_uint*)l, 16, 0, 0);
}

__device__ __forceinline__ half8 splat8(_Float16 v) {
    half8 r = {v, v, v, v, v, v, v, v};
    return r;
}

#define M_TOTAL 21760

// -------- fused weight prep (transpose+cvt+concat) and value/query f32->f16 ----
__global__ __launch_bounds__(256) void prep_cvt(
    const float* __restrict__ W_val, const float* __restrict__ W_off,
    const float* __restrict__ W_attn, const float* __restrict__ W_out,
    const float* __restrict__ b_off, const float* __restrict__ b_attn,
    const float* __restrict__ value, const float* __restrict__ query,
    _Float16* __restrict__ wt_val, _Float16* __restrict__ wt_qcat,
    _Float16* __restrict__ wt_out, float* __restrict__ bcat,
    _Float16* __restrict__ val16, _Float16* __restrict__ q16)
{
    const int r = blockIdx.x;
    const int k = threadIdx.x;
    if (r < 897) {
        if (r < 256) {
            wt_val[r * 256 + k] = (_Float16)W_val[k * 256 + r];
        } else if (r < 640) {
            const int n = r - 256;
            const float v = (n < 256) ? W_off[k * 256 + n] : W_attn[k * 128 + (n - 256)];
            wt_qcat[n * 256 + k] = (_Float16)v;
        } else if (r < 896) {
            const int n = r - 640;
            wt_out[n * 256 + k] = (_Float16)W_out[k * 256 + n];
        } else {
            bcat[k] = b_off[k];
            if (k < 128) bcat[256 + k] = b_attn[k];
        }
        return;
    }
    const size_t per = (size_t)M_TOTAL * 256 / 8;
    size_t idx = (size_t)(r - 897) * 256 + k;
    const float* src;
    _Float16* dst;
    if (idx < per) { src = value; dst = val16; }
    else { src = query; dst = q16; idx -= per; }
    const float4 lo = *(const float4*)(src + idx * 8);
    const float4 hi = *(const float4*)(src + idx * 8 + 4);
    half8 o = {(_Float16)lo.x, (_Float16)lo.y, (_Float16)lo.z, (_Float16)lo.w,
               (_Float16)hi.x, (_Float16)hi.y, (_Float16)hi.z, (_Float16)hi.w};
    *(half8*)(dst + idx * 8) = o;
}

// -------- f16 MFMA GEMM core: C[128x64 tile] = A[M,256] * Bt[NN,256]^T + bias --
// 4 waves as 2x2, wave tile 64x32 (4x2 MFMAs of 16x16x32). BK=32, DMA staging.
__device__ __forceinline__ void gemm_core(
    const _Float16* __restrict__ A, const _Float16* __restrict__ Bt,
    const float* __restrict__ bias, void* __restrict__ Cv,
    int NN, int outf16, int mt, int nt)
{
    __shared__ _Float16 Ah[128 * 32];
    __shared__ _Float16 Bh[64 * 32];

    const int tid = threadIdx.x;
    const int bm = mt * 128;
    const int bn = nt * 64;
    const int wave = tid >> 6, lane = tid & 63;
    const int wm = (wave & 1) * 64, wn = (wave >> 1) * 32;
    const int ml = lane & 15, kq = (lane >> 4) * 8;
    const int lr = lane >> 2;          // staging row within 16-row chunk
    const int lk = (lane & 3) * 8;     // staging k offset (f16)

    const f32x4 zero4 = {0.f, 0.f, 0.f, 0.f};
    f32x4 acc[4][2];
#pragma unroll
    for (int i = 0; i < 4; ++i)
#pragma unroll
        for (int j = 0; j < 2; ++j) acc[i][j] = zero4;

    for (int kt = 0; kt < 8; ++kt) {
        const int k0 = kt * 32;
        __syncthreads();
#pragma unroll
        for (int t = 0; t < 2; ++t) {
            const int row = wave * 32 + t * 16;
            load_lds16(A + (size_t)(bm + row + lr) * 256 + k0 + lk,
                       Ah + (size_t)row * 32);
        }
        {
            const int row = wave * 16;
            load_lds16(Bt + (size_t)(bn + row + lr) * 256 + k0 + lk,
                       Bh + (size_t)row * 32);
        }
        __syncthreads();

        half8 af[4], bf[2];
#pragma unroll
        for (int i = 0; i < 4; ++i)
            af[i] = *(const half8*)(Ah + (wm + i * 16 + ml) * 32 + kq);
#pragma unroll
        for (int j = 0; j < 2; ++j)
            bf[j] = *(const half8*)(Bh + (wn + j * 16 + ml) * 32 + kq);
#pragma unroll
        for (int i = 0; i < 4; ++i)
#pragma unroll
            for (int j = 0; j < 2; ++j)
                acc[i][j] = __builtin_amdgcn_mfma_f32_16x16x32_f16(af[i], bf[j], acc[i][j], 0, 0, 0);
    }

    const int r0 = (lane >> 4) * 4;
#pragma unroll
    for (int j = 0; j < 2; ++j) {
        const int col = bn + wn + j * 16 + ml;
        const float bj = bias[col];
#pragma unroll
        for (int i = 0; i < 4; ++i) {
            const size_t rbase = (size_t)(bm + wm + i * 16 + r0) * NN + col;
#pragma unroll
            for (int r = 0; r < 4; ++r) {
                const float v = acc[i][j][r] + bj;
                if (outf16)
                    ((_Float16*)Cv)[rbase + (size_t)r * NN] = (_Float16)v;
                else
                    ((float*)Cv)[rbase + (size_t)r * NN] = v;
            }
        }
    }
}

// GEMM1 (val16*wtv->valh, 680 blocks) + GEMM2 (q16*wtq->offh, 1020 blocks)
__global__ __launch_bounds__(256) void gemm12(
    const _Float16* __restrict__ val16, const _Float16* __restrict__ q16,
    const _Float16* __restrict__ wtv, const _Float16* __restrict__ wtq,
    const float* __restrict__ b_val, const float* __restrict__ bcat,
    _Float16* __restrict__ valh, _Float16* __restrict__ offh)
{
    int id = blockIdx.x;
    if (id < 680) {
        gemm_core(val16, wtv, b_val, valh, 256, 1, id >> 2, id & 3);
    } else {
        id -= 680;
        gemm_core(q16, wtq, bcat, offh, 384, 1, id / 6, id % 6);
    }
}

__global__ __launch_bounds__(256) void gemm_single(
    const _Float16* __restrict__ A, const _Float16* __restrict__ Bt,
    const float* __restrict__ bias, void* __restrict__ Cv, int NN, int outf16)
{
    const int id = blockIdx.x;
    gemm_core(A, Bt, bias, Cv, NN, outf16, id >> 2, id & 3);
}

// ---------------- sampler: identical to R3 (47us) ------------------------------
__global__ __launch_bounds__(256) void sample_f16(
    const _Float16* __restrict__ valh,   // [M,256] f16
    const float* __restrict__ refp,      // [B,Lq,4,2]
    const _Float16* __restrict__ offh,   // [M,384] f16: 0-255 offsets, 256-383 logits
    _Float16* __restrict__ acc_out)      // [M,256] f16
{
    const int wave = threadIdx.x >> 6, lane = threadIdx.x & 63;
    const int q2 = lane >> 5, sl = lane & 31;
    const int bq = blockIdx.x * 8 + wave * 2 + q2;    // 0..21759
    const int b = bq / 5440;
    const int h = sl >> 2;          // head
    const int d8 = (sl & 3) * 8;    // channel octet within head

    const _Float16* off_row = offh + (size_t)bq * 384 + h * 32;
    const _Float16* att_row = offh + (size_t)bq * 384 + 256 + h * 16;
    const float* rp = refp + (size_t)bq * 8;

    float offv[32];
#pragma unroll
    for (int i = 0; i < 4; ++i) {
        const half8 t = *(const half8*)(off_row + i * 8);
#pragma unroll
        for (int j = 0; j < 8; ++j) offv[i * 8 + j] = (float)t[j];
    }
    float lg[16];
    {
        const half8 t0 = *(const half8*)(att_row);
        const half8 t1 = *(const half8*)(att_row + 8);
#pragma unroll
        for (int j = 0; j < 8; ++j) { lg[j] = (float)t0[j]; lg[8 + j] = (float)t1[j]; }
    }
    float mx = -1e30f;
#pragma unroll
    for (int i = 0; i < 16; ++i) mx = fmaxf(mx, lg[i]);
    float s = 0.f;
#pragma unroll
    for (int i = 0; i < 16; ++i) { lg[i] = __expf(lg[i] - mx); s += lg[i]; }
    const float inv = 1.f / s;

    const float4 rp01 = *(const float4*)rp;
    const float4 rp23 = *(const float4*)(rp + 4);
    const float rxs[4] = {rp01.x, rp01.z, rp23.x, rp23.z};
    const float rys[4] = {rp01.y, rp01.w, rp23.y, rp23.w};

    const int Ws_[4] = {64, 32, 16, 8};
    const int starts_[4] = {0, 4096, 5120, 5376};

    half8 acc = splat8((_Float16)0.f);
#pragma unroll
    for (int l = 0; l < 4; ++l) {
        const int W = Ws_[l];
        const float fW = (float)W;
        const _Float16* vbase = valh + ((size_t)(b * 5440 + starts_[l])) * 256 + h * 32 + d8;
        const float rx = rxs[l], ry = rys[l];
#pragma unroll
        for (int p = 0; p < 4; ++p) {
            const int pi = l * 4 + p;
            const float aw = lg[pi] * inv;
            const float x = fmaf(rx, fW, offv[pi * 2 + 0]) - 0.5f;
            const float y = fmaf(ry, fW, offv[pi * 2 + 1]) - 0.5f;
            const float x0f = floorf(x), y0f = floorf(y);
            const int x0 = (int)x0f, y0 = (int)y0f;
            const float wx = x - x0f, wy = y - y0f;
            const bool okx0 = ((unsigned)x0 < (unsigned)W);
            const bool okx1 = ((unsigned)(x0 + 1) < (unsigned)W);
            const bool oky0 = ((unsigned)y0 < (unsigned)W);
            const bool oky1 = ((unsigned)(y0 + 1) < (unsigned)W);
            const int xc0 = min(max(x0, 0), W - 1);
            const int xc1 = min(max(x0 + 1, 0), W - 1);
            const int yc0 = min(max(y0, 0), W - 1);
            const int yc1 = min(max(y0 + 1, 0), W - 1);
            const float w00 = (okx0 & oky0) ? (1.f - wx) * (1.f - wy) * aw : 0.f;
            const float w10 = (okx1 & oky0) ? wx * (1.f - wy) * aw : 0.f;
            const float w01 = (okx0 & oky1) ? (1.f - wx) * wy * aw : 0.f;
            const float w11 = (okx1 & oky1) ? wx * wy * aw : 0.f;

            const half8 c00 = *(const half8*)(vbase + (size_t)(yc0 * W + xc0) * 256);
            const half8 c10 = *(const half8*)(vbase + (size_t)(yc0 * W + xc1) * 256);
            const half8 c01 = *(const half8*)(vbase + (size_t)(yc1 * W + xc0) * 256);
            const half8 c11 = *(const half8*)(vbase + (size_t)(yc1 * W + xc1) * 256);

            acc += c00 * splat8((_Float16)w00);
            acc += c10 * splat8((_Float16)w10);
            acc += c01 * splat8((_Float16)w01);
            acc += c11 * splat8((_Float16)w11);
        }
    }

    *(half8*)(acc_out + (size_t)bq * 256 + h * 32 + d8) = acc;
}

extern "C" void kernel_launch(void* const* d_in, const int* in_sizes, int n_in,
                              void* d_out, int out_size, void* d_ws, size_t ws_size,
                              hipStream_t stream) {
    const float* query  = (const float*)d_in[0];
    const float* refp   = (const float*)d_in[1];
    const float* value  = (const float*)d_in[2];
    const float* W_off  = (const float*)d_in[3];
    const float* b_off  = (const float*)d_in[4];
    const float* W_attn = (const float*)d_in[5];
    const float* b_attn = (const float*)d_in[6];
    const float* W_val  = (const float*)d_in[7];
    const float* b_val  = (const float*)d_in[8];
    const float* W_out  = (const float*)d_in[9];
    const float* b_out  = (const float*)d_in[10];
    float* out = (float*)d_out;

    const size_t M = M_TOTAL;

    // workspace (~50.6 MB); acc16 aliases val16 (val16 fully consumed by gemm12
    // before the sampler writes acc16 — same-stream ordering).
    _Float16* val16 = (_Float16*)d_ws;                // M*256
    _Float16* q16   = val16 + M * 256;                // M*256
    _Float16* valh  = q16 + M * 256;                  // M*256
    _Float16* offh  = valh + M * 256;                 // M*384
    _Float16* wtv   = offh + M * 384;                 // 256*256
    _Float16* wtq   = wtv + 256 * 256;                // 384*256
    _Float16* wto   = wtq + 384 * 256;                // 256*256
    float* bcat     = (float*)(wto + 256 * 256);      // 384
    _Float16* acc16 = val16;                          // alias

    dim3 blk(256);
    prep_cvt<<<dim3(897 + 5440), blk, 0, stream>>>(
        W_val, W_off, W_attn, W_out, b_off, b_attn, value, query,
        wtv, wtq, wto, bcat, val16, q16);
    gemm12<<<dim3(1700), blk, 0, stream>>>(val16, q16, wtv, wtq, b_val, bcat, valh, offh);
    sample_f16<<<dim3(M / 8), blk, 0, stream>>>(valh, refp, offh, acc16);
    gemm_single<<<dim3(680), blk, 0, stream>>>(acc16, wto, b_out, out, 256, 0);
}